// Round 5
// baseline (121.962 us; speedup 1.0000x reference)
//
#include <hip/hip_runtime.h>

// GausLJLayer: per-element LJ (3) + Gaussian (4) energy/force.
// Memory-bound (403 MB). Each thread owns 4 consecutive elements:
//  - params: 21 contiguous, 16B-aligned float4 loads (dense 21.5 KB/wave span)
//  - distance: 1 float4 load; outputs: 2 float4 nontemporal stores
// No LDS, no barrier, no vmcnt(0) drain. All indexing static (stays in VGPRs).

typedef float f32x4 __attribute__((ext_vector_type(4)));

constexpr int BLOCK = 256;
constexpr int NPAR  = 21;   // 3*3 LJ + 4*3 Gauss
constexpr int EPT   = 4;    // elements per thread

__device__ __forceinline__ void compute_one(float d, const float* __restrict__ p,
                                            float& e, float& f)
{
    const float inv_d = __builtin_amdgcn_rcpf(d);
    const float id2   = inv_d * inv_d;
    const float id6   = id2 * id2 * id2;
    const float id7   = id6 * inv_d;
    const float id12  = id6 * id6;
    const float id13  = id12 * inv_d;

    e = 0.0f; f = 0.0f;

    // LJ: p[3k+1]=c, p[3k+2]=sigma (p[3k] unused, matches reference)
    #pragma unroll
    for (int k = 0; k < 3; ++k) {
        const float c   = p[3 * k + 1];
        const float s   = p[3 * k + 2];
        const float s2  = s * s;
        const float s6  = s2 * s2 * s2;
        const float s12 = s6 * s6;
        e += 4.0f * c * (s12 * id12 - s6 * id6);
        f += -4.0f * c * (4.0f * s6 * id7 - 12.0f * s12 * id13);
    }

    // Gaussian: p[9+3k]=amplitude, +1=mean, +2=stddev
    #pragma unroll
    for (int k = 0; k < 4; ++k) {
        const float a       = p[9 + 3 * k + 0];
        const float mu      = p[9 + 3 * k + 1];
        const float sd      = p[9 + 3 * k + 2];
        const float dm      = d - mu;
        const float inv_sd2 = __builtin_amdgcn_rcpf(sd * sd);
        const float ex      = __expf(-0.5f * dm * dm * inv_sd2);
        e += a * ex;
        f += -(a * dm * ex) * (dm * dm) * inv_sd2 * inv_sd2;
    }
}

__global__ __launch_bounds__(BLOCK)
void gauslj_kernel(const float* __restrict__ distance,
                   const float* __restrict__ param,
                   float* __restrict__ out,    // [0..n) energies, [n..2n) forces
                   int n)
{
    const long long gid = (long long)blockIdx.x * BLOCK + threadIdx.x;
    const long long i0  = gid * EPT;
    if (i0 >= n) return;

    if (i0 + EPT <= n) {
        // ---- fast path: fully vectorized, all-static indexing ----
        // param slab for elems i0..i0+3: 84 floats = 21 float4, byte offset
        // i0*84 (multiple of 336 -> 16B aligned).
        const f32x4* p4 = (const f32x4*)(param + i0 * NPAR);
        float pv[EPT * NPAR];
        #pragma unroll
        for (int j = 0; j < NPAR; ++j) {
            const f32x4 v = p4[j];
            pv[4 * j + 0] = v.x; pv[4 * j + 1] = v.y;
            pv[4 * j + 2] = v.z; pv[4 * j + 3] = v.w;
        }
        const f32x4 dv = *(const f32x4*)(distance + i0);
        const float de[EPT] = {dv.x, dv.y, dv.z, dv.w};

        f32x4 eo, fo;
        float ev[EPT], fv[EPT];
        #pragma unroll
        for (int e = 0; e < EPT; ++e)
            compute_one(de[e], &pv[e * NPAR], ev[e], fv[e]);
        eo.x = ev[0]; eo.y = ev[1]; eo.z = ev[2]; eo.w = ev[3];
        fo.x = fv[0]; fo.y = fv[1]; fo.z = fv[2]; fo.w = fv[3];

        __builtin_nontemporal_store(eo, (f32x4*)(out + i0));
        __builtin_nontemporal_store(fo, (f32x4*)(out + n + i0));
    } else {
        // ---- tail: scalar per element (only the last partial thread) ----
        for (long long i = i0; i < n; ++i) {
            float pv[NPAR];
            for (int j = 0; j < NPAR; ++j) pv[j] = param[i * NPAR + j];
            float e, f;
            compute_one(distance[i], pv, e, f);
            out[i]     = e;
            out[n + i] = f;
        }
    }
}

extern "C" void kernel_launch(void* const* d_in, const int* in_sizes, int n_in,
                              void* d_out, int out_size, void* d_ws, size_t ws_size,
                              hipStream_t stream) {
    const float* distance = (const float*)d_in[0];
    const float* param    = (const float*)d_in[1];
    float* out            = (float*)d_out;
    const int n = in_sizes[0];

    const long long threads = ((long long)n + EPT - 1) / EPT;
    const int grid = (int)((threads + BLOCK - 1) / BLOCK);
    gauslj_kernel<<<grid, BLOCK, 0, stream>>>(distance, param, out, n);
}

// Round 6
// 77.613 us; speedup vs baseline: 1.5714x; 1.5714x over previous
//
#include <hip/hip_runtime.h>

// GausLJLayer: per-element LJ (3) + Gaussian (4) energy/force.
// Memory-bound (403 MB @ ~96 B/elem). R2 structure (best: 76.8 us):
// one-shot 256-thread blocks, params staged global->LDS via
// global_load_lds(16B). R6 tweak: issue the distance load BEFORE the
// staging sequence so its HBM latency hides under the vmcnt(0) drain.

constexpr int BLOCK = 256;
constexpr int NPAR  = 21;                      // 3*3 LJ + 4*3 Gauss
constexpr int NV4   = BLOCK * NPAR / 4;        // 1344 float4 per block

__global__ __launch_bounds__(BLOCK)
void gauslj_kernel(const float* __restrict__ distance,
                   const float* __restrict__ param,
                   float* __restrict__ out,    // [0..n) energies, [n..2n) forces
                   int n)
{
    __shared__ float4 sp4[NV4];                // 21504 B -> 7 blocks/CU
    float* sp = (float*)sp4;

    const int t = threadIdx.x;
    const long long base = (long long)blockIdx.x * BLOCK;
    const long long i = base + t;

    // Issue distance load FIRST: in flight during staging + vmcnt(0) drain.
    const float d = (i < n) ? distance[i] : 1.0f;

    if (base + BLOCK <= n) {
        // ---- fast path: unguarded, direct global->LDS staging ----
        const float4* g4 = (const float4*)(param + base * NPAR);
        const int wbase = t & ~63;             // wave-uniform LDS base index
        #pragma unroll
        for (int j = 0; j < 6; ++j) {
            const int idx = j * 256 + t;
            if (idx < NV4) {                   // wave-uniform predicate
                __builtin_amdgcn_global_load_lds(
                    (const __attribute__((address_space(1))) void*)(g4 + idx),
                    (__attribute__((address_space(3))) void*)(sp4 + j * 256 + wbase),
                    16, 0, 0);
            }
        }
    } else {
        // ---- tail path: guarded scalar staging (last block only) ----
        const long long gbase  = base * NPAR;
        const long long ptotal = (long long)n * NPAR;
        for (int j = 0; j < NPAR; ++j) {
            long long g = gbase + j * BLOCK + t;
            if (g < ptotal) sp[j * BLOCK + t] = param[g];
        }
    }
    __syncthreads();

    if (i >= n) return;

    const float inv_d = __builtin_amdgcn_rcpf(d);
    const float id2   = inv_d * inv_d;
    const float id6   = id2 * id2 * id2;
    const float id7   = id6 * inv_d;
    const float id12  = id6 * id6;
    const float id13  = id12 * inv_d;

    const float* p = &sp[t * NPAR];   // stride-21 rows: gcd(21,32)=1, conflict-free

    float e = 0.0f, f = 0.0f;

    // LJ: p[3k+1]=c, p[3k+2]=sigma (p[3k] unused, matches reference)
    #pragma unroll
    for (int k = 0; k < 3; ++k) {
        const float c   = p[3 * k + 1];
        const float s   = p[3 * k + 2];
        const float s2  = s * s;
        const float s6  = s2 * s2 * s2;
        const float s12 = s6 * s6;
        e += 4.0f * c * (s12 * id12 - s6 * id6);
        f += -4.0f * c * (4.0f * s6 * id7 - 12.0f * s12 * id13);
    }

    // Gaussian: p[9+3k]=amplitude, +1=mean, +2=stddev
    #pragma unroll
    for (int k = 0; k < 4; ++k) {
        const float a       = p[9 + 3 * k + 0];
        const float mu      = p[9 + 3 * k + 1];
        const float sd      = p[9 + 3 * k + 2];
        const float dm      = d - mu;
        const float inv_sd2 = __builtin_amdgcn_rcpf(sd * sd);
        const float ex      = __expf(-0.5f * dm * dm * inv_sd2);
        e += a * ex;
        f += -(a * dm * ex) * (dm * dm) * inv_sd2 * inv_sd2;
    }

    __builtin_nontemporal_store(e, &out[i]);
    __builtin_nontemporal_store(f, &out[n + i]);
}

extern "C" void kernel_launch(void* const* d_in, const int* in_sizes, int n_in,
                              void* d_out, int out_size, void* d_ws, size_t ws_size,
                              hipStream_t stream) {
    const float* distance = (const float*)d_in[0];
    const float* param    = (const float*)d_in[1];
    float* out            = (float*)d_out;
    const int n = in_sizes[0];

    const int grid = (n + BLOCK - 1) / BLOCK;
    gauslj_kernel<<<grid, BLOCK, 0, stream>>>(distance, param, out, n);
}